// Round 1
// baseline (517.373 us; speedup 1.0000x reference)
//
#include <hip/hip_runtime.h>
#include <hip/hip_bf16.h>
#include <math.h>

#define BBATCH 16
#define MTOK   16
#define NEXP   16
#define DDIM   512
#define HDIM   682
#define HPAD   704            // 11*64, padded hidden per expert
#define NHCOL  (NEXP*HDIM)    // 10912 (logits cols)
#define NHPCOL (NEXP*HPAD)    // 11264 (T1/G cols)
#define BM     (BBATCH*MTOK)  // 256 rows

// ---------------------------------------------------------------------------
// fp32 tiled GEMM: C[256 x 10912] = x[256 x 512] * phi[512 x 10912]
// ---------------------------------------------------------------------------
__global__ __launch_bounds__(256) void k_gemm_logits(
    const float* __restrict__ A, const float* __restrict__ B, float* __restrict__ C) {
    __shared__ float As[16][72];
    __shared__ float Bs[16][72];
    const int ct = blockIdx.x, rt = blockIdx.y;
    const int tid = threadIdx.x;
    const int tx = tid & 15, ty = tid >> 4;
    const int row0 = rt * 64, col0 = ct * 64;
    float acc[4][4] = {};
    for (int kb = 0; kb < 512; kb += 16) {
        { // stage A tile 64x16 (transposed into LDS)
            int r = tid >> 2, kq = (tid & 3) << 2;
            float4 a4 = *(const float4*)&A[(row0 + r) * 512 + kb + kq];
            As[kq + 0][r] = a4.x; As[kq + 1][r] = a4.y;
            As[kq + 2][r] = a4.z; As[kq + 3][r] = a4.w;
        }
        { // stage B tile 16x64
            int k = tid >> 4, cq = (tid & 15) << 2;
            int c = col0 + cq;
            float4 b4;
            if (c + 3 < NHCOL) {
                b4 = *(const float4*)&B[(kb + k) * NHCOL + c];
            } else {
                b4.x = (c + 0 < NHCOL) ? B[(kb + k) * NHCOL + c + 0] : 0.f;
                b4.y = (c + 1 < NHCOL) ? B[(kb + k) * NHCOL + c + 1] : 0.f;
                b4.z = (c + 2 < NHCOL) ? B[(kb + k) * NHCOL + c + 2] : 0.f;
                b4.w = (c + 3 < NHCOL) ? B[(kb + k) * NHCOL + c + 3] : 0.f;
            }
            *(float4*)&Bs[k][cq] = b4;
        }
        __syncthreads();
        #pragma unroll
        for (int k = 0; k < 16; ++k) {
            float4 a4 = *(const float4*)&As[k][ty * 4];
            float4 b4 = *(const float4*)&Bs[k][tx * 4];
            float av[4] = {a4.x, a4.y, a4.z, a4.w};
            float bv[4] = {b4.x, b4.y, b4.z, b4.w};
            #pragma unroll
            for (int i = 0; i < 4; ++i)
                #pragma unroll
                for (int j = 0; j < 4; ++j) acc[i][j] = fmaf(av[i], bv[j], acc[i][j]);
        }
        __syncthreads();
    }
    #pragma unroll
    for (int i = 0; i < 4; ++i) {
        int row = row0 + ty * 4 + i;
        int c = col0 + tx * 4;
        if (c + 3 < NHCOL) {
            float4 o4 = make_float4(acc[i][0], acc[i][1], acc[i][2], acc[i][3]);
            *(float4*)&C[row * NHCOL + c] = o4;
        } else {
            #pragma unroll
            for (int j = 0; j < 4; ++j)
                if (c + j < NHCOL) C[row * NHCOL + c + j] = acc[i][j];
        }
    }
}

// ---------------------------------------------------------------------------
// T1[256 x 11264] = x[256 x 512] * W1viewed[512 x 11264], col = n*704+h,
// zero for h in [682,704).  W1 is [16][512][682].
// ---------------------------------------------------------------------------
__global__ __launch_bounds__(256) void k_gemm_t1(
    const float* __restrict__ A, const float* __restrict__ W1, float* __restrict__ C) {
    __shared__ float As[16][72];
    __shared__ float Bs[16][72];
    const int ct = blockIdx.x, rt = blockIdx.y;
    const int tid = threadIdx.x;
    const int tx = tid & 15, ty = tid >> 4;
    const int row0 = rt * 64, col0 = ct * 64;
    const int n = col0 / HPAD;          // tile never straddles experts (704 = 11*64)
    const int hbase = col0 - n * HPAD;
    float acc[4][4] = {};
    for (int kb = 0; kb < 512; kb += 16) {
        {
            int r = tid >> 2, kq = (tid & 3) << 2;
            float4 a4 = *(const float4*)&A[(row0 + r) * 512 + kb + kq];
            As[kq + 0][r] = a4.x; As[kq + 1][r] = a4.y;
            As[kq + 2][r] = a4.z; As[kq + 3][r] = a4.w;
        }
        {
            int k = tid >> 4, cq = (tid & 15) << 2;
            int h = hbase + cq;
            const float* W1row = W1 + (n * 512 + kb + k) * HDIM;   // unaligned rows -> scalar loads
            float4 b4;
            b4.x = (h + 0 < HDIM) ? W1row[h + 0] : 0.f;
            b4.y = (h + 1 < HDIM) ? W1row[h + 1] : 0.f;
            b4.z = (h + 2 < HDIM) ? W1row[h + 2] : 0.f;
            b4.w = (h + 3 < HDIM) ? W1row[h + 3] : 0.f;
            *(float4*)&Bs[k][cq] = b4;
        }
        __syncthreads();
        #pragma unroll
        for (int k = 0; k < 16; ++k) {
            float4 a4 = *(const float4*)&As[k][ty * 4];
            float4 b4 = *(const float4*)&Bs[k][tx * 4];
            float av[4] = {a4.x, a4.y, a4.z, a4.w};
            float bv[4] = {b4.x, b4.y, b4.z, b4.w};
            #pragma unroll
            for (int i = 0; i < 4; ++i)
                #pragma unroll
                for (int j = 0; j < 4; ++j) acc[i][j] = fmaf(av[i], bv[j], acc[i][j]);
        }
        __syncthreads();
    }
    #pragma unroll
    for (int i = 0; i < 4; ++i) {
        int row = row0 + ty * 4 + i;
        float4 o4 = make_float4(acc[i][0], acc[i][1], acc[i][2], acc[i][3]);
        *(float4*)&C[row * NHPCOL + col0 + tx * 4] = o4;
    }
}

// ---------------------------------------------------------------------------
// Dw: softmax over m of logits[b][m][c], written as Dw[b][n][m][p]
// ---------------------------------------------------------------------------
__global__ __launch_bounds__(256) void k_dw(const float* __restrict__ L, float* __restrict__ Dw) {
    const int b = blockIdx.y;
    const int c = blockIdx.x * 256 + threadIdx.x;
    if (c >= NHCOL) return;
    float v[16];
    float mx = -1e30f;
    #pragma unroll
    for (int m = 0; m < 16; ++m) {
        v[m] = L[(b * 16 + m) * NHCOL + c];
        mx = fmaxf(mx, v[m]);
    }
    float s = 0.f;
    #pragma unroll
    for (int m = 0; m < 16; ++m) { v[m] = expf(v[m] - mx); s += v[m]; }
    float inv = 1.f / s;
    int n = c / HDIM, p = c - n * HDIM;
    #pragma unroll
    for (int m = 0; m < 16; ++m)
        Dw[((b * 16 + n) * 16 + m) * HDIM + p] = v[m] * inv;
}

// ---------------------------------------------------------------------------
// Cw: s1 = softmax over n, then softmax over p; written as Cw[b][n][m][p]
// one block per (b,m)
// ---------------------------------------------------------------------------
__global__ __launch_bounds__(256) void k_cw(const float* __restrict__ L, float* __restrict__ Cw) {
    const int m = blockIdx.x, b = blockIdx.y;
    __shared__ float row[NHCOL];
    __shared__ float red[256];
    const int tid = threadIdx.x;
    const float* Lrow = L + (b * 16 + m) * NHCOL;
    for (int i = tid; i < NHCOL; i += 256) row[i] = Lrow[i];
    __syncthreads();
    // softmax over n for each p
    for (int p = tid; p < HDIM; p += 256) {
        float v[16];
        float mx = -1e30f;
        #pragma unroll
        for (int n = 0; n < 16; ++n) { v[n] = row[n * HDIM + p]; mx = fmaxf(mx, v[n]); }
        float s = 0.f;
        #pragma unroll
        for (int n = 0; n < 16; ++n) { v[n] = expf(v[n] - mx); s += v[n]; }
        float inv = 1.f / s;
        #pragma unroll
        for (int n = 0; n < 16; ++n) row[n * HDIM + p] = v[n] * inv;
    }
    __syncthreads();
    // softmax over p for each n (values in (0,1]: no max-shift needed)
    for (int n = 0; n < 16; ++n) {
        float ps = 0.f;
        for (int p = tid; p < HDIM; p += 256) ps += expf(row[n * HDIM + p]);
        red[tid] = ps;
        __syncthreads();
        #pragma unroll
        for (int s = 128; s > 0; s >>= 1) {
            if (tid < s) red[tid] += red[tid + s];
            __syncthreads();
        }
        float inv = 1.f / red[0];
        for (int p = tid; p < HDIM; p += 256)
            Cw[((b * 16 + n) * 16 + m) * HDIM + p] = expf(row[n * HDIM + p]) * inv;
        __syncthreads();
    }
}

// ---------------------------------------------------------------------------
// Fused middle: per (b,n) block:
//   G[m][h] = sum_p Cw[m,p] * relu( sum_m' Dw[m',p]*T1[m',h] + b1[h] )
// hmid is never materialized. Dw/Cw chunk-staged (double buffer) in LDS.
// ---------------------------------------------------------------------------
#define PCH 64
__global__ __launch_bounds__(256) void k_mid(
    const float* __restrict__ T1g, const float* __restrict__ Dwg,
    const float* __restrict__ Cwg, const float* __restrict__ b1,
    float* __restrict__ Gg) {
    const int n = blockIdx.x, b = blockIdx.y;
    __shared__ float DwS[2][PCH * 16];  // [p][m]
    __shared__ float CwS[2][PCH * 16];
    const int tid = threadIdx.x;
    const float* dwg = Dwg + (b * 16 + n) * (16 * HDIM);
    const float* cwg = Cwg + (b * 16 + n) * (16 * HDIM);

    // per-thread T1 fragments: 3 h-columns, 16 m each
    float t1[3][16];
    float bias[3];
    #pragma unroll
    for (int j = 0; j < 3; ++j) {
        int h = tid + j * 256;
        if (h < HDIM) {
            bias[j] = b1[n * HDIM + h];
            #pragma unroll
            for (int m = 0; m < 16; ++m)
                t1[j][m] = T1g[(b * 16 + m) * NHPCOL + n * HPAD + h];
        } else {
            bias[j] = -1e30f;   // relu -> 0, so this column contributes nothing
            #pragma unroll
            for (int m = 0; m < 16; ++m) t1[j][m] = 0.f;
        }
    }
    float g[3][16] = {};

    // stage chunk 0
    for (int i = tid; i < PCH * 16; i += 256) {
        int m = i >> 6, p = i & 63;
        DwS[0][p * 16 + m] = dwg[m * HDIM + p];
        CwS[0][p * 16 + m] = cwg[m * HDIM + p];
    }
    __syncthreads();

    int cur = 0;
    for (int c0 = 0; c0 < HDIM; c0 += PCH) {
        // prefetch next chunk into the other buffer
        int nc0 = c0 + PCH;
        if (nc0 < HDIM) {
            int lim = (HDIM - nc0 < PCH) ? (HDIM - nc0) : PCH;
            for (int i = tid; i < lim * 16; i += 256) {
                int m = i / lim, p = i - m * lim;
                DwS[1 - cur][p * 16 + m] = dwg[m * HDIM + nc0 + p];
                CwS[1 - cur][p * 16 + m] = cwg[m * HDIM + nc0 + p];
            }
        }
        int pe = (HDIM - c0 < PCH) ? (HDIM - c0) : PCH;
        for (int pp = 0; pp < pe; ++pp) {
            float dw[16], cw[16];
            #pragma unroll
            for (int q = 0; q < 4; ++q) {
                float4 d4 = *(const float4*)&DwS[cur][pp * 16 + q * 4];
                dw[q * 4 + 0] = d4.x; dw[q * 4 + 1] = d4.y;
                dw[q * 4 + 2] = d4.z; dw[q * 4 + 3] = d4.w;
                float4 c4 = *(const float4*)&CwS[cur][pp * 16 + q * 4];
                cw[q * 4 + 0] = c4.x; cw[q * 4 + 1] = c4.y;
                cw[q * 4 + 2] = c4.z; cw[q * 4 + 3] = c4.w;
            }
            #pragma unroll
            for (int j = 0; j < 3; ++j) {
                float v = bias[j];
                #pragma unroll
                for (int m = 0; m < 16; ++m) v = fmaf(dw[m], t1[j][m], v);
                v = fmaxf(v, 0.f);
                #pragma unroll
                for (int m = 0; m < 16; ++m) g[j][m] = fmaf(cw[m], v, g[j][m]);
            }
        }
        __syncthreads();
        cur = 1 - cur;
    }

    // write G[b][m][n*704+h] (+ zero the h-pad region)
    #pragma unroll
    for (int j = 0; j < 3; ++j) {
        int h = tid + j * 256;
        if (h < HDIM) {
            #pragma unroll
            for (int m = 0; m < 16; ++m)
                Gg[(b * 16 + m) * NHPCOL + n * HPAD + h] = g[j][m];
        }
    }
    if (tid < HPAD - HDIM) {
        int h = HDIM + tid;
        #pragma unroll
        for (int m = 0; m < 16; ++m)
            Gg[(b * 16 + m) * NHPCOL + n * HPAD + h] = 0.f;
    }
}

// ---------------------------------------------------------------------------
// K5: per-expert partial  P5[n][bm][d] = sum_h G[bm][n*704+h] * W2[n][h][d]
// (K split by expert; W2 rows h>=682 treated as zero)
// ---------------------------------------------------------------------------
__global__ __launch_bounds__(256) void k_gemm_y(
    const float* __restrict__ G, const float* __restrict__ W2, float* __restrict__ P5) {
    __shared__ float As[16][72];
    __shared__ float Bs[16][72];
    const int ct = blockIdx.x;          // 8 col tiles over d
    const int rt = blockIdx.y;          // 4 row tiles over bm
    const int n = blockIdx.z;           // expert = K chunk
    const int tid = threadIdx.x;
    const int tx = tid & 15, ty = tid >> 4;
    const int row0 = rt * 64, col0 = ct * 64;
    const int ncol = n * HPAD;
    float acc[4][4] = {};
    for (int kb = 0; kb < HPAD; kb += 16) {
        {
            int r = tid >> 2, kq = (tid & 3) << 2;
            float4 a4 = *(const float4*)&G[(row0 + r) * NHPCOL + ncol + kb + kq];
            As[kq + 0][r] = a4.x; As[kq + 1][r] = a4.y;
            As[kq + 2][r] = a4.z; As[kq + 3][r] = a4.w;
        }
        {
            int k = tid >> 4, cq = (tid & 15) << 2;
            int h = kb + k;
            float4 b4 = make_float4(0.f, 0.f, 0.f, 0.f);
            if (h < HDIM) b4 = *(const float4*)&W2[(n * HDIM + h) * 512 + col0 + cq];
            *(float4*)&Bs[k][cq] = b4;
        }
        __syncthreads();
        #pragma unroll
        for (int k = 0; k < 16; ++k) {
            float4 a4 = *(const float4*)&As[k][ty * 4];
            float4 b4 = *(const float4*)&Bs[k][tx * 4];
            float av[4] = {a4.x, a4.y, a4.z, a4.w};
            float bv[4] = {b4.x, b4.y, b4.z, b4.w};
            #pragma unroll
            for (int i = 0; i < 4; ++i)
                #pragma unroll
                for (int j = 0; j < 4; ++j) acc[i][j] = fmaf(av[i], bv[j], acc[i][j]);
        }
        __syncthreads();
    }
    #pragma unroll
    for (int i = 0; i < 4; ++i) {
        int row = row0 + ty * 4 + i;
        float4 o4 = make_float4(acc[i][0], acc[i][1], acc[i][2], acc[i][3]);
        *(float4*)&P5[n * (BM * 512) + row * 512 + col0 + tx * 4] = o4;
    }
}

// Y[bm][d] = sum_n P5[n][bm][d] + sum_n b2[n][d]
__global__ __launch_bounds__(256) void k_yred(
    const float* __restrict__ P5, const float* __restrict__ b2, float* __restrict__ Y) {
    const int idx = blockIdx.x * 256 + threadIdx.x;   // 131072
    const int d = idx & 511;
    float s = 0.f;
    #pragma unroll
    for (int n = 0; n < 16; ++n) s += P5[n * (BM * 512) + idx];
    #pragma unroll
    for (int n = 0; n < 16; ++n) s += b2[n * 512 + d];
    Y[idx] = s;
}

// ---------------------------------------------------------------------------
// Final: out[b][o] = bout[o] + sum_k Y[b][k] * Wout[k][o], K=8192 split by 16
// ---------------------------------------------------------------------------
__global__ __launch_bounds__(256) void k_out_part(
    const float* __restrict__ Y, const float* __restrict__ Wout, float* __restrict__ P6) {
    const int ot = blockIdx.x;   // 8
    const int kc = blockIdx.y;   // 16
    __shared__ float Ys[16 * 512];
    const int tid = threadIdx.x;
    for (int i = tid; i < 8192; i += 256) {
        int bb = i >> 9, kk = i & 511;
        Ys[i] = Y[bb * 8192 + kc * 512 + kk];
    }
    __syncthreads();
    const int o = ot * 64 + (tid & 63);
    const int bg = tid >> 6;
    float acc[4] = {};
    for (int kk = 0; kk < 512; ++kk) {
        float w = Wout[(kc * 512 + kk) * 512 + o];
        #pragma unroll
        for (int i = 0; i < 4; ++i) acc[i] = fmaf(Ys[(bg * 4 + i) * 512 + kk], w, acc[i]);
    }
    #pragma unroll
    for (int i = 0; i < 4; ++i)
        P6[kc * 8192 + (bg * 4 + i) * 512 + o] = acc[i];
}

__global__ __launch_bounds__(256) void k_out_red(
    const float* __restrict__ P6, const float* __restrict__ bout, float* __restrict__ out) {
    const int idx = blockIdx.x * 256 + threadIdx.x;   // 8192
    const int o = idx & 511;
    float s = bout[o];
    #pragma unroll
    for (int kc = 0; kc < 16; ++kc) s += P6[kc * 8192 + idx];
    out[idx] = s;
}

// ---------------------------------------------------------------------------
extern "C" void kernel_launch(void* const* d_in, const int* in_sizes, int n_in,
                              void* d_out, int out_size, void* d_ws, size_t ws_size,
                              hipStream_t stream) {
    const float* x    = (const float*)d_in[0];
    const float* phi  = (const float*)d_in[1];
    const float* W1   = (const float*)d_in[2];
    const float* b1   = (const float*)d_in[3];
    const float* W2   = (const float*)d_in[4];
    const float* b2   = (const float*)d_in[5];
    const float* Wout = (const float*)d_in[6];
    const float* bout = (const float*)d_in[7];
    float* out = (float*)d_out;

    float* ws     = (float*)d_ws;
    float* logits = ws;                    // 256*10912      = 2,793,472
    float* T1     = logits + 2793472;      // 256*11264      = 2,883,584
    float* Dw     = T1 + 2883584;          // 16*16*16*682   = 2,793,472
    float* Cw     = Dw + 2793472;          // 2,793,472
    float* G      = Cw + 2793472;          // 2,883,584
    float* P5     = G + 2883584;           // 16*256*512     = 2,097,152
    float* Y      = P5 + 2097152;          // 131,072
    float* P6     = Y + 131072;            // 131,072        (total ~66 MB)

    k_gemm_logits<<<dim3(171, 4), 256, 0, stream>>>(x, phi, logits);
    k_gemm_t1   <<<dim3(176, 4), 256, 0, stream>>>(x, W1, T1);
    k_dw        <<<dim3(43, 16), 256, 0, stream>>>(logits, Dw);
    k_cw        <<<dim3(16, 16), 256, 0, stream>>>(logits, Cw);
    k_mid       <<<dim3(16, 16), 256, 0, stream>>>(T1, Dw, Cw, b1, G);
    k_gemm_y    <<<dim3(8, 4, 16), 256, 0, stream>>>(G, W2, P5);
    k_yred      <<<dim3(512), 256, 0, stream>>>(P5, b2, Y);
    k_out_part  <<<dim3(8, 16), 256, 0, stream>>>(Y, Wout, P6);
    k_out_red   <<<dim3(32), 256, 0, stream>>>(P6, bout, out);
}

// Round 2
// 462.856 us; speedup vs baseline: 1.1178x; 1.1178x over previous
//
#include <hip/hip_runtime.h>
#include <hip/hip_bf16.h>
#include <math.h>

#define BBATCH 16
#define MTOK   16
#define NEXP   16
#define DDIM   512
#define HDIM   682
#define HPAD   704            // 11*64, padded hidden per expert
#define NHCOL  (NEXP*HDIM)    // 10912 (logits cols)
#define NHPCOL (NEXP*HPAD)    // 11264 (T1/G cols)
#define BM     (BBATCH*MTOK)  // 256 rows

// ---------------------------------------------------------------------------
// fp32 tiled GEMM: C[256 x 10912] = x[256 x 512] * phi[512 x 10912]
// ---------------------------------------------------------------------------
__global__ __launch_bounds__(256) void k_gemm_logits(
    const float* __restrict__ A, const float* __restrict__ B, float* __restrict__ C) {
    __shared__ float As[16][72];
    __shared__ float Bs[16][72];
    const int ct = blockIdx.x, rt = blockIdx.y;
    const int tid = threadIdx.x;
    const int tx = tid & 15, ty = tid >> 4;
    const int row0 = rt * 64, col0 = ct * 64;
    float acc[4][4] = {};
    for (int kb = 0; kb < 512; kb += 16) {
        { // stage A tile 64x16 (transposed into LDS)
            int r = tid >> 2, kq = (tid & 3) << 2;
            float4 a4 = *(const float4*)&A[(row0 + r) * 512 + kb + kq];
            As[kq + 0][r] = a4.x; As[kq + 1][r] = a4.y;
            As[kq + 2][r] = a4.z; As[kq + 3][r] = a4.w;
        }
        { // stage B tile 16x64
            int k = tid >> 4, cq = (tid & 15) << 2;
            int c = col0 + cq;
            float4 b4;
            if (c + 3 < NHCOL) {
                b4 = *(const float4*)&B[(kb + k) * NHCOL + c];
            } else {
                b4.x = (c + 0 < NHCOL) ? B[(kb + k) * NHCOL + c + 0] : 0.f;
                b4.y = (c + 1 < NHCOL) ? B[(kb + k) * NHCOL + c + 1] : 0.f;
                b4.z = (c + 2 < NHCOL) ? B[(kb + k) * NHCOL + c + 2] : 0.f;
                b4.w = (c + 3 < NHCOL) ? B[(kb + k) * NHCOL + c + 3] : 0.f;
            }
            *(float4*)&Bs[k][cq] = b4;
        }
        __syncthreads();
        #pragma unroll
        for (int k = 0; k < 16; ++k) {
            float4 a4 = *(const float4*)&As[k][ty * 4];
            float4 b4 = *(const float4*)&Bs[k][tx * 4];
            float av[4] = {a4.x, a4.y, a4.z, a4.w};
            float bv[4] = {b4.x, b4.y, b4.z, b4.w};
            #pragma unroll
            for (int i = 0; i < 4; ++i)
                #pragma unroll
                for (int j = 0; j < 4; ++j) acc[i][j] = fmaf(av[i], bv[j], acc[i][j]);
        }
        __syncthreads();
    }
    #pragma unroll
    for (int i = 0; i < 4; ++i) {
        int row = row0 + ty * 4 + i;
        int c = col0 + tx * 4;
        if (c + 3 < NHCOL) {
            float4 o4 = make_float4(acc[i][0], acc[i][1], acc[i][2], acc[i][3]);
            *(float4*)&C[row * NHCOL + c] = o4;
        } else {
            #pragma unroll
            for (int j = 0; j < 4; ++j)
                if (c + j < NHCOL) C[row * NHCOL + c + j] = acc[i][j];
        }
    }
}

// ---------------------------------------------------------------------------
// T1[256 x 11264] = x[256 x 512] * W1viewed[512 x 11264], col = n*704+h
// ---------------------------------------------------------------------------
__global__ __launch_bounds__(256) void k_gemm_t1(
    const float* __restrict__ A, const float* __restrict__ W1, float* __restrict__ C) {
    __shared__ float As[16][72];
    __shared__ float Bs[16][72];
    const int ct = blockIdx.x, rt = blockIdx.y;
    const int tid = threadIdx.x;
    const int tx = tid & 15, ty = tid >> 4;
    const int row0 = rt * 64, col0 = ct * 64;
    const int n = col0 / HPAD;
    const int hbase = col0 - n * HPAD;
    float acc[4][4] = {};
    for (int kb = 0; kb < 512; kb += 16) {
        {
            int r = tid >> 2, kq = (tid & 3) << 2;
            float4 a4 = *(const float4*)&A[(row0 + r) * 512 + kb + kq];
            As[kq + 0][r] = a4.x; As[kq + 1][r] = a4.y;
            As[kq + 2][r] = a4.z; As[kq + 3][r] = a4.w;
        }
        {
            int k = tid >> 4, cq = (tid & 15) << 2;
            int h = hbase + cq;
            const float* W1row = W1 + (n * 512 + kb + k) * HDIM;
            float4 b4;
            b4.x = (h + 0 < HDIM) ? W1row[h + 0] : 0.f;
            b4.y = (h + 1 < HDIM) ? W1row[h + 1] : 0.f;
            b4.z = (h + 2 < HDIM) ? W1row[h + 2] : 0.f;
            b4.w = (h + 3 < HDIM) ? W1row[h + 3] : 0.f;
            *(float4*)&Bs[k][cq] = b4;
        }
        __syncthreads();
        #pragma unroll
        for (int k = 0; k < 16; ++k) {
            float4 a4 = *(const float4*)&As[k][ty * 4];
            float4 b4 = *(const float4*)&Bs[k][tx * 4];
            float av[4] = {a4.x, a4.y, a4.z, a4.w};
            float bv[4] = {b4.x, b4.y, b4.z, b4.w};
            #pragma unroll
            for (int i = 0; i < 4; ++i)
                #pragma unroll
                for (int j = 0; j < 4; ++j) acc[i][j] = fmaf(av[i], bv[j], acc[i][j]);
        }
        __syncthreads();
    }
    #pragma unroll
    for (int i = 0; i < 4; ++i) {
        int row = row0 + ty * 4 + i;
        float4 o4 = make_float4(acc[i][0], acc[i][1], acc[i][2], acc[i][3]);
        *(float4*)&C[row * NHPCOL + col0 + tx * 4] = o4;
    }
}

// ---------------------------------------------------------------------------
// Dw: softmax over m of logits[b][m][c], written as Dw[b][n][m][p]
// ---------------------------------------------------------------------------
__global__ __launch_bounds__(256) void k_dw(const float* __restrict__ L, float* __restrict__ Dw) {
    const int b = blockIdx.y;
    const int c = blockIdx.x * 256 + threadIdx.x;
    if (c >= NHCOL) return;
    float v[16];
    float mx = -1e30f;
    #pragma unroll
    for (int m = 0; m < 16; ++m) {
        v[m] = L[(b * 16 + m) * NHCOL + c];
        mx = fmaxf(mx, v[m]);
    }
    float s = 0.f;
    #pragma unroll
    for (int m = 0; m < 16; ++m) { v[m] = expf(v[m] - mx); s += v[m]; }
    float inv = 1.f / s;
    int n = c / HDIM, p = c - n * HDIM;
    #pragma unroll
    for (int m = 0; m < 16; ++m)
        Dw[((b * 16 + n) * 16 + m) * HDIM + p] = v[m] * inv;
}

// ---------------------------------------------------------------------------
// Cw: s1 = softmax over n, then softmax over p; written as Cw[b][n][m][p]
// ---------------------------------------------------------------------------
__global__ __launch_bounds__(256) void k_cw(const float* __restrict__ L, float* __restrict__ Cw) {
    const int m = blockIdx.x, b = blockIdx.y;
    __shared__ float row[NHCOL];
    __shared__ float red[256];
    const int tid = threadIdx.x;
    const float* Lrow = L + (b * 16 + m) * NHCOL;
    for (int i = tid; i < NHCOL; i += 256) row[i] = Lrow[i];
    __syncthreads();
    for (int p = tid; p < HDIM; p += 256) {
        float v[16];
        float mx = -1e30f;
        #pragma unroll
        for (int n = 0; n < 16; ++n) { v[n] = row[n * HDIM + p]; mx = fmaxf(mx, v[n]); }
        float s = 0.f;
        #pragma unroll
        for (int n = 0; n < 16; ++n) { v[n] = expf(v[n] - mx); s += v[n]; }
        float inv = 1.f / s;
        #pragma unroll
        for (int n = 0; n < 16; ++n) row[n * HDIM + p] = v[n] * inv;
    }
    __syncthreads();
    for (int n = 0; n < 16; ++n) {
        float ps = 0.f;
        for (int p = tid; p < HDIM; p += 256) ps += expf(row[n * HDIM + p]);
        red[tid] = ps;
        __syncthreads();
        #pragma unroll
        for (int s = 128; s > 0; s >>= 1) {
            if (tid < s) red[tid] += red[tid + s];
            __syncthreads();
        }
        float inv = 1.f / red[0];
        for (int p = tid; p < HDIM; p += 256)
            Cw[((b * 16 + n) * 16 + m) * HDIM + p] = expf(row[n * HDIM + p]) * inv;
        __syncthreads();
    }
}

// ---------------------------------------------------------------------------
// Zero G (incl. pad columns) before atomic accumulation
// ---------------------------------------------------------------------------
__global__ __launch_bounds__(256) void k_zero(float* __restrict__ p, int n4) {
    int i = blockIdx.x * 256 + threadIdx.x;
    if (i < n4) *(float4*)&p[i * 4] = make_float4(0.f, 0.f, 0.f, 0.f);
}

// ---------------------------------------------------------------------------
// Fused middle, p-split x4: per (n, b, ps) block over p-slice:
//   G[m][h] += sum_{p in slice} Cw[m,p] * relu( sum_m' Dw[m',p]*T1[m',h] + b1[h] )
// Partials accumulated with atomicAdd into pre-zeroed G.
// LDS layout [p][20] pad: conflict-reduced writes, 16B-aligned float4 reads.
// ---------------------------------------------------------------------------
#define PCH 64
#define PSLICE 171   // ceil(682/4)
__global__ __launch_bounds__(256) void k_mid(
    const float* __restrict__ T1g, const float* __restrict__ Dwg,
    const float* __restrict__ Cwg, const float* __restrict__ b1,
    float* __restrict__ Gg) {
    const int n = blockIdx.x, b = blockIdx.y, ps = blockIdx.z;
    __shared__ float DwS[2][PCH * 20];
    __shared__ float CwS[2][PCH * 20];
    const int tid = threadIdx.x;
    const float* dwg = Dwg + (b * 16 + n) * (16 * HDIM);
    const float* cwg = Cwg + (b * 16 + n) * (16 * HDIM);
    const int p0 = ps * PSLICE;
    const int pend = (p0 + PSLICE < HDIM) ? (p0 + PSLICE) : HDIM;

    // per-thread T1 fragments: 3 h-columns, 16 m each
    float t1[3][16];
    float bias[3];
    #pragma unroll
    for (int j = 0; j < 3; ++j) {
        int h = tid + j * 256;
        if (h < HDIM) {
            bias[j] = b1[n * HDIM + h];
            #pragma unroll
            for (int m = 0; m < 16; ++m)
                t1[j][m] = T1g[(b * 16 + m) * NHPCOL + n * HPAD + h];
        } else {
            bias[j] = -1e30f;   // relu -> 0
            #pragma unroll
            for (int m = 0; m < 16; ++m) t1[j][m] = 0.f;
        }
    }
    float g[3][16] = {};

    // stage chunk 0
    {
        int lim0 = (pend - p0 < PCH) ? (pend - p0) : PCH;
        for (int i = tid; i < lim0 * 16; i += 256) {
            int m = i / lim0, p = i - m * lim0;
            DwS[0][p * 20 + m] = dwg[m * HDIM + p0 + p];
            CwS[0][p * 20 + m] = cwg[m * HDIM + p0 + p];
        }
    }
    __syncthreads();

    int cur = 0;
    for (int c0 = p0; c0 < pend; c0 += PCH) {
        int nc0 = c0 + PCH;
        if (nc0 < pend) {
            int lim = (pend - nc0 < PCH) ? (pend - nc0) : PCH;
            for (int i = tid; i < lim * 16; i += 256) {
                int m = i / lim, p = i - m * lim;
                DwS[1 - cur][p * 20 + m] = dwg[m * HDIM + nc0 + p];
                CwS[1 - cur][p * 20 + m] = cwg[m * HDIM + nc0 + p];
            }
        }
        int pe = (pend - c0 < PCH) ? (pend - c0) : PCH;
        for (int pp = 0; pp < pe; ++pp) {
            float dw[16], cw[16];
            #pragma unroll
            for (int q = 0; q < 4; ++q) {
                float4 d4 = *(const float4*)&DwS[cur][pp * 20 + q * 4];
                dw[q * 4 + 0] = d4.x; dw[q * 4 + 1] = d4.y;
                dw[q * 4 + 2] = d4.z; dw[q * 4 + 3] = d4.w;
                float4 c4 = *(const float4*)&CwS[cur][pp * 20 + q * 4];
                cw[q * 4 + 0] = c4.x; cw[q * 4 + 1] = c4.y;
                cw[q * 4 + 2] = c4.z; cw[q * 4 + 3] = c4.w;
            }
            #pragma unroll
            for (int j = 0; j < 3; ++j) {
                float v = bias[j];
                #pragma unroll
                for (int m = 0; m < 16; ++m) v = fmaf(dw[m], t1[j][m], v);
                v = fmaxf(v, 0.f);
                #pragma unroll
                for (int m = 0; m < 16; ++m) g[j][m] = fmaf(cw[m], v, g[j][m]);
            }
        }
        __syncthreads();
        cur = 1 - cur;
    }

    // accumulate partial into pre-zeroed G (pad region stays zero)
    #pragma unroll
    for (int j = 0; j < 3; ++j) {
        int h = tid + j * 256;
        if (h < HDIM) {
            #pragma unroll
            for (int m = 0; m < 16; ++m)
                atomicAdd(&Gg[(b * 16 + m) * NHPCOL + n * HPAD + h], g[j][m]);
        }
    }
}

// ---------------------------------------------------------------------------
// K5: per-expert partial  P5[n][bm][d] = sum_h G[bm][n*704+h] * W2[n][h][d]
// ---------------------------------------------------------------------------
__global__ __launch_bounds__(256) void k_gemm_y(
    const float* __restrict__ G, const float* __restrict__ W2, float* __restrict__ P5) {
    __shared__ float As[16][72];
    __shared__ float Bs[16][72];
    const int ct = blockIdx.x;
    const int rt = blockIdx.y;
    const int n = blockIdx.z;
    const int tid = threadIdx.x;
    const int tx = tid & 15, ty = tid >> 4;
    const int row0 = rt * 64, col0 = ct * 64;
    const int ncol = n * HPAD;
    float acc[4][4] = {};
    for (int kb = 0; kb < HPAD; kb += 16) {
        {
            int r = tid >> 2, kq = (tid & 3) << 2;
            float4 a4 = *(const float4*)&G[(row0 + r) * NHPCOL + ncol + kb + kq];
            As[kq + 0][r] = a4.x; As[kq + 1][r] = a4.y;
            As[kq + 2][r] = a4.z; As[kq + 3][r] = a4.w;
        }
        {
            int k = tid >> 4, cq = (tid & 15) << 2;
            int h = kb + k;
            float4 b4 = make_float4(0.f, 0.f, 0.f, 0.f);
            if (h < HDIM) b4 = *(const float4*)&W2[(n * HDIM + h) * 512 + col0 + cq];
            *(float4*)&Bs[k][cq] = b4;
        }
        __syncthreads();
        #pragma unroll
        for (int k = 0; k < 16; ++k) {
            float4 a4 = *(const float4*)&As[k][ty * 4];
            float4 b4 = *(const float4*)&Bs[k][tx * 4];
            float av[4] = {a4.x, a4.y, a4.z, a4.w};
            float bv[4] = {b4.x, b4.y, b4.z, b4.w};
            #pragma unroll
            for (int i = 0; i < 4; ++i)
                #pragma unroll
                for (int j = 0; j < 4; ++j) acc[i][j] = fmaf(av[i], bv[j], acc[i][j]);
        }
        __syncthreads();
    }
    #pragma unroll
    for (int i = 0; i < 4; ++i) {
        int row = row0 + ty * 4 + i;
        float4 o4 = make_float4(acc[i][0], acc[i][1], acc[i][2], acc[i][3]);
        *(float4*)&P5[n * (BM * 512) + row * 512 + col0 + tx * 4] = o4;
    }
}

// Y[bm][d] = sum_n P5[n][bm][d] + sum_n b2[n][d]
__global__ __launch_bounds__(256) void k_yred(
    const float* __restrict__ P5, const float* __restrict__ b2, float* __restrict__ Y) {
    const int idx = blockIdx.x * 256 + threadIdx.x;
    const int d = idx & 511;
    float s = 0.f;
    #pragma unroll
    for (int n = 0; n < 16; ++n) s += P5[n * (BM * 512) + idx];
    #pragma unroll
    for (int n = 0; n < 16; ++n) s += b2[n * 512 + d];
    Y[idx] = s;
}

// ---------------------------------------------------------------------------
// Final: out[b][o] = bout[o] + sum_k Y[b][k] * Wout[k][o], K=8192 split by 16
// ---------------------------------------------------------------------------
__global__ __launch_bounds__(256) void k_out_part(
    const float* __restrict__ Y, const float* __restrict__ Wout, float* __restrict__ P6) {
    const int ot = blockIdx.x;
    const int kc = blockIdx.y;
    __shared__ float Ys[16 * 512];
    const int tid = threadIdx.x;
    for (int i = tid; i < 8192; i += 256) {
        int bb = i >> 9, kk = i & 511;
        Ys[i] = Y[bb * 8192 + kc * 512 + kk];
    }
    __syncthreads();
    const int o = ot * 64 + (tid & 63);
    const int bg = tid >> 6;
    float acc[4] = {};
    for (int kk = 0; kk < 512; ++kk) {
        float w = Wout[(kc * 512 + kk) * 512 + o];
        #pragma unroll
        for (int i = 0; i < 4; ++i) acc[i] = fmaf(Ys[(bg * 4 + i) * 512 + kk], w, acc[i]);
    }
    #pragma unroll
    for (int i = 0; i < 4; ++i)
        P6[kc * 8192 + (bg * 4 + i) * 512 + o] = acc[i];
}

__global__ __launch_bounds__(256) void k_out_red(
    const float* __restrict__ P6, const float* __restrict__ bout, float* __restrict__ out) {
    const int idx = blockIdx.x * 256 + threadIdx.x;
    const int o = idx & 511;
    float s = bout[o];
    #pragma unroll
    for (int kc = 0; kc < 16; ++kc) s += P6[kc * 8192 + idx];
    out[idx] = s;
}

// ---------------------------------------------------------------------------
extern "C" void kernel_launch(void* const* d_in, const int* in_sizes, int n_in,
                              void* d_out, int out_size, void* d_ws, size_t ws_size,
                              hipStream_t stream) {
    const float* x    = (const float*)d_in[0];
    const float* phi  = (const float*)d_in[1];
    const float* W1   = (const float*)d_in[2];
    const float* b1   = (const float*)d_in[3];
    const float* W2   = (const float*)d_in[4];
    const float* b2   = (const float*)d_in[5];
    const float* Wout = (const float*)d_in[6];
    const float* bout = (const float*)d_in[7];
    float* out = (float*)d_out;

    float* ws     = (float*)d_ws;
    float* logits = ws;                    // 2,793,472
    float* T1     = logits + 2793472;      // 2,883,584
    float* Dw     = T1 + 2883584;          // 2,793,472
    float* Cw     = Dw + 2793472;          // 2,793,472
    float* G      = Cw + 2793472;          // 2,883,584
    float* P5     = G + 2883584;           // 2,097,152
    float* Y      = P5 + 2097152;          // 131,072
    float* P6     = Y + 131072;            // 131,072   (total ~66 MB)

    k_gemm_logits<<<dim3(171, 4), 256, 0, stream>>>(x, phi, logits);
    k_gemm_t1   <<<dim3(176, 4), 256, 0, stream>>>(x, W1, T1);
    k_dw        <<<dim3(43, 16), 256, 0, stream>>>(logits, Dw);
    k_cw        <<<dim3(16, 16), 256, 0, stream>>>(logits, Cw);
    k_zero      <<<dim3((2883584 / 4 + 255) / 256), 256, 0, stream>>>(G, 2883584 / 4);
    k_mid       <<<dim3(16, 16, 4), 256, 0, stream>>>(T1, Dw, Cw, b1, G);
    k_gemm_y    <<<dim3(8, 4, 16), 256, 0, stream>>>(G, W2, P5);
    k_yred      <<<dim3(512), 256, 0, stream>>>(P5, b2, Y);
    k_out_part  <<<dim3(8, 16), 256, 0, stream>>>(Y, Wout, P6);
    k_out_red   <<<dim3(32), 256, 0, stream>>>(P6, bout, out);
}

// Round 3
// 301.497 us; speedup vs baseline: 1.7160x; 1.5352x over previous
//
#include <hip/hip_runtime.h>
#include <hip/hip_bf16.h>
#include <math.h>

typedef unsigned int   u32;
typedef unsigned short u16;
typedef __bf16 bf16;
typedef bf16  bf16x8 __attribute__((ext_vector_type(8)));
typedef float f32x4  __attribute__((ext_vector_type(4)));

#define BBATCH 16
#define MTOK   16
#define NEXP   16
#define DDIM   512
#define HDIM   682
#define HPAD   704            // 11*64
#define NHCOL  (NEXP*HDIM)    // 10912
#define NHPCOL (NEXP*HPAD)    // 11264
#define BM     (BBATCH*MTOK)  // 256

__device__ __forceinline__ u16 f2bf(float f) {
    u32 u = __builtin_bit_cast(u32, f);
    u += 0x7fffu + ((u >> 16) & 1u);
    return (u16)(u >> 16);
}

// ---------------------------------------------------------------------------
// fp32 tiled GEMM: logits[256 x 10912] = x[256 x 512] * phi[512 x 10912]
// (kept fp32: logits feed softmax, bf16 rounding there is too risky)
// ---------------------------------------------------------------------------
__global__ __launch_bounds__(256) void k_gemm_logits(
    const float* __restrict__ A, const float* __restrict__ B, float* __restrict__ C) {
    __shared__ float As[16][72];
    __shared__ float Bs[16][72];
    const int ct = blockIdx.x, rt = blockIdx.y;
    const int tid = threadIdx.x;
    const int tx = tid & 15, ty = tid >> 4;
    const int row0 = rt * 64, col0 = ct * 64;
    float acc[4][4] = {};
    for (int kb = 0; kb < 512; kb += 16) {
        {
            int r = tid >> 2, kq = (tid & 3) << 2;
            float4 a4 = *(const float4*)&A[(row0 + r) * 512 + kb + kq];
            As[kq + 0][r] = a4.x; As[kq + 1][r] = a4.y;
            As[kq + 2][r] = a4.z; As[kq + 3][r] = a4.w;
        }
        {
            int k = tid >> 4, cq = (tid & 15) << 2;
            int c = col0 + cq;
            float4 b4;
            if (c + 3 < NHCOL) {
                b4 = *(const float4*)&B[(kb + k) * NHCOL + c];
            } else {
                b4.x = (c + 0 < NHCOL) ? B[(kb + k) * NHCOL + c + 0] : 0.f;
                b4.y = (c + 1 < NHCOL) ? B[(kb + k) * NHCOL + c + 1] : 0.f;
                b4.z = (c + 2 < NHCOL) ? B[(kb + k) * NHCOL + c + 2] : 0.f;
                b4.w = (c + 3 < NHCOL) ? B[(kb + k) * NHCOL + c + 3] : 0.f;
            }
            *(float4*)&Bs[k][cq] = b4;
        }
        __syncthreads();
        #pragma unroll
        for (int k = 0; k < 16; ++k) {
            float4 a4 = *(const float4*)&As[k][ty * 4];
            float4 b4 = *(const float4*)&Bs[k][tx * 4];
            float av[4] = {a4.x, a4.y, a4.z, a4.w};
            float bv[4] = {b4.x, b4.y, b4.z, b4.w};
            #pragma unroll
            for (int i = 0; i < 4; ++i)
                #pragma unroll
                for (int j = 0; j < 4; ++j) acc[i][j] = fmaf(av[i], bv[j], acc[i][j]);
        }
        __syncthreads();
    }
    #pragma unroll
    for (int i = 0; i < 4; ++i) {
        int row = row0 + ty * 4 + i;
        int c = col0 + tx * 4;
        if (c + 3 < NHCOL) {
            *(float4*)&C[row * NHCOL + c] = make_float4(acc[i][0], acc[i][1], acc[i][2], acc[i][3]);
        } else {
            #pragma unroll
            for (int j = 0; j < 4; ++j)
                if (c + j < NHCOL) C[row * NHCOL + c + j] = acc[i][j];
        }
    }
}

// ---------------------------------------------------------------------------
// x -> bf16 (xb[256][512])
// ---------------------------------------------------------------------------
__global__ __launch_bounds__(256) void k_cast_x(const float* __restrict__ x, u16* __restrict__ xb) {
    int i = (blockIdx.x * 256 + threadIdx.x) * 4;
    float4 v = *(const float4*)&x[i];
    u16 o[4] = {f2bf(v.x), f2bf(v.y), f2bf(v.z), f2bf(v.w)};
    *(uint2*)&xb[i] = make_uint2((u32)o[0] | ((u32)o[1] << 16), (u32)o[2] | ((u32)o[3] << 16));
}

// ---------------------------------------------------------------------------
// W1[16][512][682] -> W1T[n*704+h][k=512] bf16 (zero h>=682)
// grid (kt=8, ht=11, n=16)
// ---------------------------------------------------------------------------
__global__ __launch_bounds__(256) void k_t_w1(const float* __restrict__ W1, u16* __restrict__ W1T) {
    __shared__ float Ls[64][65];
    const int kt = blockIdx.x, ht = blockIdx.y, n = blockIdx.z;
    const int tid = threadIdx.x;
    {
        int r = tid >> 2, cg = (tid & 3) << 4;
        const float* src = W1 + (size_t)(n * 512 + kt * 64 + r) * HDIM + ht * 64;
        #pragma unroll
        for (int i = 0; i < 16; ++i) {
            int c = cg + i, h = ht * 64 + c;
            Ls[r][c] = (h < HDIM) ? src[c] : 0.f;
        }
    }
    __syncthreads();
    {
        int cc = tid & 63, kq = tid >> 6;
        u16 tmp[16];
        #pragma unroll
        for (int i = 0; i < 16; ++i) tmp[i] = f2bf(Ls[kq * 16 + i][cc]);
        u16* dst = W1T + (size_t)(n * HPAD + ht * 64 + cc) * 512 + kt * 64 + kq * 16;
        *(uint4*)dst = *(uint4*)&tmp[0];
        *(uint4*)(dst + 8) = *(uint4*)&tmp[8];
    }
}

// ---------------------------------------------------------------------------
// W2[16][682][512] -> W2T[d][n*704+h] bf16 (zero h>=682)
// grid (dt=8, ht=11, n=16)
// ---------------------------------------------------------------------------
__global__ __launch_bounds__(256) void k_t_w2(const float* __restrict__ W2, u16* __restrict__ W2T) {
    __shared__ float Ls[64][65];
    const int dt = blockIdx.x, ht = blockIdx.y, n = blockIdx.z;
    const int tid = threadIdx.x;
    {
        int r = tid >> 2, cg = (tid & 3) << 4;       // r = h-local, c = d-local
        int h = ht * 64 + r;
        if (h < HDIM) {
            const float* src = W2 + (size_t)(n * HDIM + h) * 512 + dt * 64 + cg;
            float4 v0 = *(const float4*)&src[0];
            float4 v1 = *(const float4*)&src[4];
            float4 v2 = *(const float4*)&src[8];
            float4 v3 = *(const float4*)&src[12];
            *(float4*)&Ls[r][cg + 0]  = v0; *(float4*)&Ls[r][cg + 4]  = v1;
            *(float4*)&Ls[r][cg + 8]  = v2; *(float4*)&Ls[r][cg + 12] = v3;
        } else {
            #pragma unroll
            for (int i = 0; i < 16; ++i) Ls[r][cg + i] = 0.f;
        }
    }
    __syncthreads();
    {
        int cc = tid & 63, kq = tid >> 6;            // cc = d-local, kq*16+i = h-local
        u16 tmp[16];
        #pragma unroll
        for (int i = 0; i < 16; ++i) tmp[i] = f2bf(Ls[kq * 16 + i][cc]);
        u16* dst = W2T + (size_t)(dt * 64 + cc) * NHPCOL + n * HPAD + ht * 64 + kq * 16;
        *(uint4*)dst = *(uint4*)&tmp[0];
        *(uint4*)(dst + 8) = *(uint4*)&tmp[8];
    }
}

// ---------------------------------------------------------------------------
// Wout[8192][512] -> WoutT[o][k] bf16.  grid (kt=128, ot=8)
// ---------------------------------------------------------------------------
__global__ __launch_bounds__(256) void k_t_wout(const float* __restrict__ W, u16* __restrict__ WT) {
    __shared__ float Ls[64][65];
    const int kt = blockIdx.x, ot = blockIdx.y;
    const int tid = threadIdx.x;
    {
        int r = tid >> 2, cg = (tid & 3) << 4;
        const float* src = W + (size_t)(kt * 64 + r) * 512 + ot * 64 + cg;
        float4 v0 = *(const float4*)&src[0];
        float4 v1 = *(const float4*)&src[4];
        float4 v2 = *(const float4*)&src[8];
        float4 v3 = *(const float4*)&src[12];
        *(float4*)&Ls[r][cg + 0]  = v0; *(float4*)&Ls[r][cg + 4]  = v1;
        *(float4*)&Ls[r][cg + 8]  = v2; *(float4*)&Ls[r][cg + 12] = v3;
    }
    __syncthreads();
    {
        int cc = tid & 63, kq = tid >> 6;
        u16 tmp[16];
        #pragma unroll
        for (int i = 0; i < 16; ++i) tmp[i] = f2bf(Ls[kq * 16 + i][cc]);
        u16* dst = WT + (size_t)(ot * 64 + cc) * 8192 + kt * 64 + kq * 16;
        *(uint4*)dst = *(uint4*)&tmp[0];
        *(uint4*)(dst + 8) = *(uint4*)&tmp[8];
    }
}

// ---------------------------------------------------------------------------
// Dw softmax over m  ->  DwT[b][n][p(704, zero-pad)][16 m] bf16
// grid (44, 16): c in [0,11264)
// ---------------------------------------------------------------------------
__global__ __launch_bounds__(256) void k_dw(const float* __restrict__ L, u16* __restrict__ DwT) {
    const int b = blockIdx.y;
    const int c = blockIdx.x * 256 + threadIdx.x;      // n*704+p
    const int n = c / HPAD, p = c - n * HPAD;
    u16 o[16];
    if (p < HDIM) {
        float v[16];
        float mx = -1e30f;
        #pragma unroll
        for (int m = 0; m < 16; ++m) {
            v[m] = L[(b * 16 + m) * NHCOL + n * HDIM + p];
            mx = fmaxf(mx, v[m]);
        }
        float s = 0.f;
        #pragma unroll
        for (int m = 0; m < 16; ++m) { v[m] = expf(v[m] - mx); s += v[m]; }
        float inv = 1.f / s;
        #pragma unroll
        for (int m = 0; m < 16; ++m) o[m] = f2bf(v[m] * inv);
    } else {
        #pragma unroll
        for (int m = 0; m < 16; ++m) o[m] = 0;
    }
    u16* dst = DwT + (size_t)((b * 16 + n) * HPAD + p) * 16;
    *(uint4*)dst = *(uint4*)&o[0];
    *(uint4*)(dst + 8) = *(uint4*)&o[8];
}

// ---------------------------------------------------------------------------
// Cw = softmax_p(softmax_n(logits)) -> CwB[b][n][m][704 p] bf16 (zero-pad p)
// block per (m=bx, b=by); 4 waves x 4 n each
// ---------------------------------------------------------------------------
__global__ __launch_bounds__(256) void k_cw(const float* __restrict__ L, u16* __restrict__ CwB) {
    const int m = blockIdx.x, b = blockIdx.y;
    __shared__ float row[NHCOL];
    const int tid = threadIdx.x;
    const float* Lrow = L + (size_t)(b * 16 + m) * NHCOL;
    for (int i = tid; i < NHCOL; i += 256) row[i] = Lrow[i];
    __syncthreads();
    for (int p = tid; p < HDIM; p += 256) {
        float v[16];
        float mx = -1e30f;
        #pragma unroll
        for (int n = 0; n < 16; ++n) { v[n] = row[n * HDIM + p]; mx = fmaxf(mx, v[n]); }
        float s = 0.f;
        #pragma unroll
        for (int n = 0; n < 16; ++n) { v[n] = expf(v[n] - mx); s += v[n]; }
        float inv = 1.f / s;
        #pragma unroll
        for (int n = 0; n < 16; ++n) row[n * HDIM + p] = v[n] * inv;
    }
    __syncthreads();
    const int wv = tid >> 6, lane = tid & 63;
    for (int nn = 0; nn < 4; ++nn) {
        int n = wv * 4 + nn;
        float s = 0.f;
        for (int p = lane; p < HDIM; p += 64) s += expf(row[n * HDIM + p]);
        #pragma unroll
        for (int off = 32; off > 0; off >>= 1) s += __shfl_xor(s, off);
        float inv = 1.f / s;
        u16* dst = CwB + (size_t)(((b * 16 + n) * 16 + m)) * HPAD;
        for (int p = lane; p < HDIM; p += 64) dst[p] = f2bf(expf(row[n * HDIM + p]) * inv);
        if (lane < HPAD - HDIM) dst[HDIM + lane] = 0;
    }
}

// ---------------------------------------------------------------------------
// MFMA GEMM: T1b[256][11264] bf16 = xb[256][512] * W1T^T
// grid (ct=88, rt=2); 128x128 tile, 4 waves of 64x64
// ---------------------------------------------------------------------------
__global__ __launch_bounds__(256) void k_t1gemm(
    const u16* __restrict__ A, const u16* __restrict__ BT, u16* __restrict__ C) {
    __shared__ u16 AsL[128 * 40];
    __shared__ u16 BsL[128 * 40];
    const int ct = blockIdx.x, rt = blockIdx.y;
    const int tid = threadIdx.x;
    const int wv = tid >> 6, lane = tid & 63, quad = lane >> 4, l15 = lane & 15;
    const int mb = (wv & 1) * 64, nb = (wv >> 1) * 64;
    f32x4 acc[4][4] = {};
    for (int kb = 0; kb < 512; kb += 32) {
        {
            int r = tid >> 1, kg = (tid & 1) * 16;
            const u16* s = A + (size_t)(rt * 128 + r) * 512 + kb + kg;
            *(uint4*)&AsL[r * 40 + kg]     = *(const uint4*)s;
            *(uint4*)&AsL[r * 40 + kg + 8] = *(const uint4*)(s + 8);
            const u16* t = BT + (size_t)(ct * 128 + r) * 512 + kb + kg;
            *(uint4*)&BsL[r * 40 + kg]     = *(const uint4*)t;
            *(uint4*)&BsL[r * 40 + kg + 8] = *(const uint4*)(t + 8);
        }
        __syncthreads();
        bf16x8 af[4], bf[4];
        #pragma unroll
        for (int i = 0; i < 4; ++i) {
            af[i] = *(const bf16x8*)&AsL[(mb + i * 16 + l15) * 40 + quad * 8];
            bf[i] = *(const bf16x8*)&BsL[(nb + i * 16 + l15) * 40 + quad * 8];
        }
        #pragma unroll
        for (int i = 0; i < 4; ++i)
            #pragma unroll
            for (int j = 0; j < 4; ++j)
                acc[i][j] = __builtin_amdgcn_mfma_f32_16x16x32_bf16(af[i], bf[j], acc[i][j], 0, 0, 0);
        __syncthreads();
    }
    #pragma unroll
    for (int i = 0; i < 4; ++i)
        #pragma unroll
        for (int j = 0; j < 4; ++j) {
            int col = ct * 128 + nb + j * 16 + l15;
            int r0  = rt * 128 + mb + i * 16 + quad * 4;
            #pragma unroll
            for (int r = 0; r < 4; ++r)
                C[(size_t)(r0 + r) * NHPCOL + col] = f2bf(acc[i][j][r]);
        }
}

// ---------------------------------------------------------------------------
// Fused middle (MFMA): per (htile, n, b):
//   hmid[p][h] = relu(b1[h] + sum_m Dw[m][p]*T1[m][h])   (K=16, zero-padded)
//   G[m][h]   += sum_p Cw[m][p]*hmid[p][h]
// No barriers in the chunk loop: each wave owns its 32 h-rows of hmidT.
// grid (6, 16, 16)
// ---------------------------------------------------------------------------
__global__ __launch_bounds__(256) void k_mid(
    const u16* __restrict__ T1b, const u16* __restrict__ DwT,
    const u16* __restrict__ CwB, const float* __restrict__ b1,
    u16* __restrict__ Gb) {
    __shared__ u16 T1T[128 * 24];     // [h-local][m], cols 16 live
    __shared__ u16 hmidT[128 * 72];   // [h-local][p-local 64], stride 72
    const int ht = blockIdx.x, n = blockIdx.y, b = blockIdx.z;
    const int tid = threadIdx.x;
    const int wv = tid >> 6, lane = tid & 63, quad = lane >> 4, l15 = lane & 15;
    const int h0 = ht * 128;
    const int b16n = b * 16 + n;

    // stage T1 tile [16 m][128 h] -> T1T[h][m]
    {
        int m = tid & 15, hh0 = (tid >> 4) * 8;
        u16 v[8];
        if (h0 + hh0 < HPAD) {
            *(uint4*)v = *(const uint4*)(T1b + (size_t)(b * 16 + m) * NHPCOL + n * HPAD + h0 + hh0);
        } else {
            #pragma unroll
            for (int i = 0; i < 8; ++i) v[i] = 0;
        }
        #pragma unroll
        for (int i = 0; i < 8; ++i) T1T[(hh0 + i) * 24 + m] = v[i];
    }
    __syncthreads();

    // per-wave stage1 B-frags (constant across chunks) + bias
    bf16x8 bt1[2];
    float biasv[2];
    #pragma unroll
    for (int hj = 0; hj < 2; ++hj) {
        bf16x8 z = {};
        bt1[hj] = z;
        if (lane < 32)
            bt1[hj] = *(const bf16x8*)&T1T[(wv * 32 + hj * 16 + l15) * 24 + quad * 8];
        int h = h0 + wv * 32 + hj * 16 + l15;
        biasv[hj] = (h < HDIM) ? b1[n * HDIM + h] : 0.f;
    }

    f32x4 acc[2] = {};
    for (int c = 0; c < 11; ++c) {
        const int p0 = c * 64;
        // ---- stage1: hmid chunk [64 p][32 h(own)] ----
        #pragma unroll
        for (int pi = 0; pi < 4; ++pi) {
            bf16x8 adw = {};
            if (lane < 32)
                adw = *(const bf16x8*)(DwT + (size_t)((b16n * HPAD) + p0 + pi * 16 + l15) * 16 + quad * 8);
            #pragma unroll
            for (int hj = 0; hj < 2; ++hj) {
                f32x4 z = {};
                f32x4 hm = __builtin_amdgcn_mfma_f32_16x16x32_bf16(adw, bt1[hj], z, 0, 0, 0);
                u16 pk[4];
                #pragma unroll
                for (int r = 0; r < 4; ++r) pk[r] = f2bf(fmaxf(hm[r] + biasv[hj], 0.f));
                int hrow = wv * 32 + hj * 16 + l15;
                *(uint2*)&hmidT[hrow * 72 + pi * 16 + quad * 4] =
                    make_uint2((u32)pk[0] | ((u32)pk[1] << 16), (u32)pk[2] | ((u32)pk[3] << 16));
            }
        }
        // ---- stage2: G[16 m][32 h(own)] += Cw * hmid ----
        #pragma unroll
        for (int s = 0; s < 2; ++s) {
            bf16x8 acw = *(const bf16x8*)(CwB + (size_t)(b16n * 16 + l15) * HPAD + p0 + s * 32 + quad * 8);
            #pragma unroll
            for (int hj = 0; hj < 2; ++hj) {
                bf16x8 bh = *(const bf16x8*)&hmidT[(wv * 32 + hj * 16 + l15) * 72 + s * 32 + quad * 8];
                acc[hj] = __builtin_amdgcn_mfma_f32_16x16x32_bf16(acw, bh, acc[hj], 0, 0, 0);
            }
        }
    }
    // epilogue: G bf16
    #pragma unroll
    for (int hj = 0; hj < 2; ++hj) {
        int h = h0 + wv * 32 + hj * 16 + l15;
        if (h < HPAD) {
            #pragma unroll
            for (int r = 0; r < 4; ++r) {
                int m = quad * 4 + r;
                Gb[(size_t)(b * 16 + m) * NHPCOL + n * HPAD + h] = f2bf(acc[hj][r]);
            }
        }
    }
}

// ---------------------------------------------------------------------------
// Y init: Y[bm][d] = sum_n b2[n][d]
// ---------------------------------------------------------------------------
__global__ __launch_bounds__(256) void k_yinit(const float* __restrict__ b2, float* __restrict__ Y) {
    int idx = blockIdx.x * 256 + threadIdx.x;
    int d = idx & 511;
    float s = 0.f;
    #pragma unroll
    for (int nn = 0; nn < 16; ++nn) s += b2[nn * 512 + d];
    Y[idx] = s;
}

// ---------------------------------------------------------------------------
// MFMA split-K GEMM: Y[256][512] += Gb[.., n-slice] * W2T[d][n-slice]^T
// grid (ct=4, rt=4, n=16); 64x128 tile, 4 waves of 64x32
// ---------------------------------------------------------------------------
__global__ __launch_bounds__(256) void k_ygemm(
    const u16* __restrict__ G, const u16* __restrict__ W2T, float* __restrict__ Y) {
    __shared__ u16 AsL[64 * 40];
    __shared__ u16 BsL[128 * 40];
    const int ct = blockIdx.x, rt = blockIdx.y, n = blockIdx.z;
    const int tid = threadIdx.x;
    const int wv = tid >> 6, lane = tid & 63, quad = lane >> 4, l15 = lane & 15;
    const int m0 = rt * 64, d0 = ct * 128;
    f32x4 acc[4][2] = {};
    for (int kb = 0; kb < HPAD; kb += 32) {
        {
            int am = tid >> 2, akg = (tid & 3) * 8;
            *(uint4*)&AsL[am * 40 + akg] =
                *(const uint4*)(G + (size_t)(m0 + am) * NHPCOL + n * HPAD + kb + akg);
            int bc = tid >> 1, bkg = (tid & 1) * 16;
            const u16* t = W2T + (size_t)(d0 + bc) * NHPCOL + n * HPAD + kb + bkg;
            *(uint4*)&BsL[bc * 40 + bkg]     = *(const uint4*)t;
            *(uint4*)&BsL[bc * 40 + bkg + 8] = *(const uint4*)(t + 8);
        }
        __syncthreads();
        bf16x8 af[4], bf[2];
        #pragma unroll
        for (int i = 0; i < 4; ++i) af[i] = *(const bf16x8*)&AsL[(i * 16 + l15) * 40 + quad * 8];
        #pragma unroll
        for (int j = 0; j < 2; ++j) bf[j] = *(const bf16x8*)&BsL[(wv * 32 + j * 16 + l15) * 40 + quad * 8];
        #pragma unroll
        for (int i = 0; i < 4; ++i)
            #pragma unroll
            for (int j = 0; j < 2; ++j)
                acc[i][j] = __builtin_amdgcn_mfma_f32_16x16x32_bf16(af[i], bf[j], acc[i][j], 0, 0, 0);
        __syncthreads();
    }
    #pragma unroll
    for (int i = 0; i < 4; ++i)
        #pragma unroll
        for (int j = 0; j < 2; ++j) {
            int d = d0 + wv * 32 + j * 16 + l15;
            int r0 = m0 + i * 16 + quad * 4;
            #pragma unroll
            for (int r = 0; r < 4; ++r)
                atomicAdd(&Y[(size_t)(r0 + r) * 512 + d], acc[i][j][r]);
        }
}

// ---------------------------------------------------------------------------
// out init: out[b][o] = bout[o]
// ---------------------------------------------------------------------------
__global__ __launch_bounds__(256) void k_outinit(const float* __restrict__ bout, float* __restrict__ out) {
    int idx = blockIdx.x * 256 + threadIdx.x;
    out[idx] = bout[idx & 511];
}

// ---------------------------------------------------------------------------
// MFMA split-K GEMM: out[16][512] += Yflat[16][k-slice] * WoutT[o][k-slice]^T
// grid (ct=4, ks=16); block: 16x128 tile over K=512, 4 waves of 16x32
// ---------------------------------------------------------------------------
__global__ __launch_bounds__(256) void k_outgemm(
    const float* __restrict__ Y, const u16* __restrict__ WoutT, float* __restrict__ out) {
    __shared__ u16 AsL[16 * 40];
    __shared__ u16 BsL[128 * 40];
    const int ct = blockIdx.x, ks = blockIdx.y;
    const int tid = threadIdx.x;
    const int wv = tid >> 6, lane = tid & 63, quad = lane >> 4, l15 = lane & 15;
    const int o0 = ct * 128, kbase = ks * 512;
    f32x4 acc[2] = {};
    for (int kb = 0; kb < 512; kb += 32) {
        {
            int r = tid >> 4, k2 = (tid & 15) * 2;
            float2 v = *(const float2*)&Y[(size_t)r * 8192 + kbase + kb + k2];
            AsL[r * 40 + k2]     = f2bf(v.x);
            AsL[r * 40 + k2 + 1] = f2bf(v.y);
            int bc = tid >> 1, bkg = (tid & 1) * 16;
            const u16* t = WoutT + (size_t)(o0 + bc) * 8192 + kbase + kb + bkg;
            *(uint4*)&BsL[bc * 40 + bkg]     = *(const uint4*)t;
            *(uint4*)&BsL[bc * 40 + bkg + 8] = *(const uint4*)(t + 8);
        }
        __syncthreads();
        bf16x8 af = *(const bf16x8*)&AsL[l15 * 40 + quad * 8];
        #pragma unroll
        for (int j = 0; j < 2; ++j) {
            bf16x8 bf = *(const bf16x8*)&BsL[(wv * 32 + j * 16 + l15) * 40 + quad * 8];
            acc[j] = __builtin_amdgcn_mfma_f32_16x16x32_bf16(af, bf, acc[j], 0, 0, 0);
        }
        __syncthreads();
    }
    #pragma unroll
    for (int j = 0; j < 2; ++j) {
        int o = o0 + wv * 32 + j * 16 + l15;
        #pragma unroll
        for (int r = 0; r < 4; ++r)
            atomicAdd(&out[(size_t)(quad * 4 + r) * 512 + o], acc[j][r]);
    }
}

// ---------------------------------------------------------------------------
extern "C" void kernel_launch(void* const* d_in, const int* in_sizes, int n_in,
                              void* d_out, int out_size, void* d_ws, size_t ws_size,
                              hipStream_t stream) {
    const float* x    = (const float*)d_in[0];
    const float* phi  = (const float*)d_in[1];
    const float* W1   = (const float*)d_in[2];
    const float* b1   = (const float*)d_in[3];
    const float* W2   = (const float*)d_in[4];
    const float* b2   = (const float*)d_in[5];
    const float* Wout = (const float*)d_in[6];
    const float* bout = (const float*)d_in[7];
    float* out = (float*)d_out;

    char* base = (char*)d_ws;
    float* logits = (float*)(base + 0);            // 11,173,888 B
    u16*   DwT    = (u16*)(base + 11173888);       //  5,767,168
    u16*   CwB    = (u16*)(base + 16941056);       //  5,767,168
    u16*   T1b    = (u16*)(base + 22708224);       //  5,767,168
    u16*   Gb     = (u16*)(base + 28475392);       //  5,767,168
    u16*   xb     = (u16*)(base + 34242560);       //    262,144
    u16*   W1T    = (u16*)(base + 34504704);       // 11,534,336
    u16*   W2T    = (u16*)(base + 46039040);       // 11,534,336
    u16*   WoutT  = (u16*)(base + 57573376);       //  8,388,608
    float* Y      = (float*)(base + 65961984);     //    524,288   (end 66,486,272)

    k_cast_x     <<<dim3(128), 256, 0, stream>>>(x, xb);
    k_t_w1       <<<dim3(8, 11, 16), 256, 0, stream>>>(W1, W1T);
    k_t_w2       <<<dim3(8, 11, 16), 256, 0, stream>>>(W2, W2T);
    k_t_wout     <<<dim3(128, 8), 256, 0, stream>>>(Wout, WoutT);
    k_gemm_logits<<<dim3(171, 4), 256, 0, stream>>>(x, phi, logits);
    k_dw         <<<dim3(44, 16), 256, 0, stream>>>(logits, DwT);
    k_cw         <<<dim3(16, 16), 256, 0, stream>>>(logits, CwB);
    k_t1gemm     <<<dim3(88, 2), 256, 0, stream>>>(xb, W1T, T1b);
    k_mid        <<<dim3(6, 16, 16), 256, 0, stream>>>(T1b, DwT, CwB, b1, Gb);
    k_yinit      <<<dim3(512), 256, 0, stream>>>(b2, Y);
    k_ygemm      <<<dim3(4, 4, 16), 256, 0, stream>>>(Gb, W2T, Y);
    k_outinit    <<<dim3(32), 256, 0, stream>>>(bout, out);
    k_outgemm    <<<dim3(4, 16), 256, 0, stream>>>(Y, WoutT, out);
}

// Round 5
// 294.612 us; speedup vs baseline: 1.7561x; 1.0234x over previous
//
#include <hip/hip_runtime.h>
#include <hip/hip_bf16.h>
#include <math.h>

typedef unsigned int   u32;
typedef unsigned short u16;
typedef __bf16 bf16;
typedef bf16  bf16x8 __attribute__((ext_vector_type(8)));
typedef float f32x4  __attribute__((ext_vector_type(4)));

#define BBATCH 16
#define MTOK   16
#define NEXP   16
#define DDIM   512
#define HDIM   682
#define HPAD   704            // 11*64
#define NHCOL  (NEXP*HDIM)    // 10912
#define NHPCOL (NEXP*HPAD)    // 11264
#define BM     (BBATCH*MTOK)  // 256
#define CPAD   10944          // 171*64, padded logits-col count for phiT

__device__ __forceinline__ u16 f2bf(float f) {
    u32 u = __builtin_bit_cast(u32, f);
    u += 0x7fffu + ((u >> 16) & 1u);
    return (u16)(u >> 16);
}
__device__ __forceinline__ float bf2f(u16 h) {
    u32 u = ((u32)h) << 16;
    return __builtin_bit_cast(float, u);
}

// ---------------------------------------------------------------------------
// x -> bf16 hi/lo planes (xh, xl [256][512])
// ---------------------------------------------------------------------------
__global__ __launch_bounds__(256) void k_split_x(
    const float* __restrict__ x, u16* __restrict__ xh, u16* __restrict__ xl) {
    int i = (blockIdx.x * 256 + threadIdx.x) * 4;
    float4 v = *(const float4*)&x[i];
    float a[4] = {v.x, v.y, v.z, v.w};
    u16 hh[4], ll[4];
    #pragma unroll
    for (int j = 0; j < 4; ++j) {
        hh[j] = f2bf(a[j]);
        ll[j] = f2bf(a[j] - bf2f(hh[j]));
    }
    *(uint2*)&xh[i] = make_uint2((u32)hh[0] | ((u32)hh[1] << 16), (u32)hh[2] | ((u32)hh[3] << 16));
    *(uint2*)&xl[i] = make_uint2((u32)ll[0] | ((u32)ll[1] << 16), (u32)ll[2] | ((u32)ll[3] << 16));
}

// ---------------------------------------------------------------------------
// phi [512][10912] fp32 -> phiT_hi/lo [10944][512] bf16 (zero c>=10912)
// grid (kt=8, ct=171)
// ---------------------------------------------------------------------------
__global__ __launch_bounds__(256) void k_t_phi(
    const float* __restrict__ phi, u16* __restrict__ ph, u16* __restrict__ pl) {
    __shared__ float Ls[64][65];
    const int kt = blockIdx.x, ct = blockIdx.y;
    const int tid = threadIdx.x;
    {
        int r = tid >> 2, cg = (tid & 3) << 4;
        const float* src = phi + (size_t)(kt * 64 + r) * NHCOL + ct * 64 + cg;
        #pragma unroll
        for (int j = 0; j < 4; ++j) {
            int c0 = ct * 64 + cg + j * 4;
            float4 v = (c0 + 4 <= NHCOL) ? *(const float4*)&src[j * 4]
                                         : make_float4(0.f, 0.f, 0.f, 0.f);
            *(float4*)&Ls[r][cg + j * 4] = v;
        }
    }
    __syncthreads();
    {
        int cc = tid & 63, kq = tid >> 6;
        u16 th[16], tl[16];
        #pragma unroll
        for (int i = 0; i < 16; ++i) {
            float v = Ls[kq * 16 + i][cc];
            th[i] = f2bf(v);
            tl[i] = f2bf(v - bf2f(th[i]));
        }
        size_t off = (size_t)(ct * 64 + cc) * 512 + kt * 64 + kq * 16;
        *(uint4*)(ph + off)     = *(uint4*)&th[0];
        *(uint4*)(ph + off + 8) = *(uint4*)&th[8];
        *(uint4*)(pl + off)     = *(uint4*)&tl[0];
        *(uint4*)(pl + off + 8) = *(uint4*)&tl[8];
    }
}

// ---------------------------------------------------------------------------
// Split-bf16 MFMA GEMM: logits[256][10912] fp32 =
//   (xh+xl)[256][512] * (ph+pl)^T   (3-product decomposition)
// grid (ct=171, rt=4); 64x64 tile, 4 waves of 16x64
// ---------------------------------------------------------------------------
__global__ __launch_bounds__(256) void k_lgemm(
    const u16* __restrict__ xh, const u16* __restrict__ xl,
    const u16* __restrict__ ph, const u16* __restrict__ pl,
    float* __restrict__ C) {
    __shared__ u16 AH[64 * 40], AL[64 * 40], BH[64 * 40], BL[64 * 40];
    const int ct = blockIdx.x, rt = blockIdx.y;
    const int tid = threadIdx.x;
    const int wv = tid >> 6, lane = tid & 63, quad = lane >> 4, l15 = lane & 15;
    f32x4 acc[4] = {};
    for (int kb = 0; kb < 512; kb += 32) {
        {
            int r = tid >> 2, kg = (tid & 3) * 8;
            size_t ao = (size_t)(rt * 64 + r) * 512 + kb + kg;
            size_t bo = (size_t)(ct * 64 + r) * 512 + kb + kg;
            *(uint4*)&AH[r * 40 + kg] = *(const uint4*)(xh + ao);
            *(uint4*)&AL[r * 40 + kg] = *(const uint4*)(xl + ao);
            *(uint4*)&BH[r * 40 + kg] = *(const uint4*)(ph + bo);
            *(uint4*)&BL[r * 40 + kg] = *(const uint4*)(pl + bo);
        }
        __syncthreads();
        bf16x8 ah = *(const bf16x8*)&AH[(wv * 16 + l15) * 40 + quad * 8];
        bf16x8 al = *(const bf16x8*)&AL[(wv * 16 + l15) * 40 + quad * 8];
        #pragma unroll
        for (int j = 0; j < 4; ++j) {
            bf16x8 bh = *(const bf16x8*)&BH[(j * 16 + l15) * 40 + quad * 8];
            bf16x8 bl = *(const bf16x8*)&BL[(j * 16 + l15) * 40 + quad * 8];
            acc[j] = __builtin_amdgcn_mfma_f32_16x16x32_bf16(ah, bh, acc[j], 0, 0, 0);
            acc[j] = __builtin_amdgcn_mfma_f32_16x16x32_bf16(ah, bl, acc[j], 0, 0, 0);
            acc[j] = __builtin_amdgcn_mfma_f32_16x16x32_bf16(al, bh, acc[j], 0, 0, 0);
        }
        __syncthreads();
    }
    #pragma unroll
    for (int j = 0; j < 4; ++j) {
        int col = ct * 64 + j * 16 + l15;
        if (col < NHCOL) {
            int r0 = rt * 64 + wv * 16 + quad * 4;
            #pragma unroll
            for (int r = 0; r < 4; ++r)
                C[(size_t)(r0 + r) * NHCOL + col] = acc[j][r];
        }
    }
}

// ---------------------------------------------------------------------------
// W1[16][512][682] -> W1T[n*704+h][k=512] bf16 (zero h>=682)
// grid (kt=8, ht=11, n=16)
// ---------------------------------------------------------------------------
__global__ __launch_bounds__(256) void k_t_w1(const float* __restrict__ W1, u16* __restrict__ W1T) {
    __shared__ float Ls[64][65];
    const int kt = blockIdx.x, ht = blockIdx.y, n = blockIdx.z;
    const int tid = threadIdx.x;
    {
        int r = tid >> 2, cg = (tid & 3) << 4;
        const float* src = W1 + (size_t)(n * 512 + kt * 64 + r) * HDIM + ht * 64;
        #pragma unroll
        for (int i = 0; i < 16; ++i) {
            int c = cg + i, h = ht * 64 + c;
            Ls[r][c] = (h < HDIM) ? src[c] : 0.f;
        }
    }
    __syncthreads();
    {
        int cc = tid & 63, kq = tid >> 6;
        u16 tmp[16];
        #pragma unroll
        for (int i = 0; i < 16; ++i) tmp[i] = f2bf(Ls[kq * 16 + i][cc]);
        u16* dst = W1T + (size_t)(n * HPAD + ht * 64 + cc) * 512 + kt * 64 + kq * 16;
        *(uint4*)dst = *(uint4*)&tmp[0];
        *(uint4*)(dst + 8) = *(uint4*)&tmp[8];
    }
}

// ---------------------------------------------------------------------------
// W2[16][682][512] -> W2T[d][n*704+h] bf16 (zero h>=682)
// grid (dt=8, ht=11, n=16)
// ---------------------------------------------------------------------------
__global__ __launch_bounds__(256) void k_t_w2(const float* __restrict__ W2, u16* __restrict__ W2T) {
    __shared__ float Ls[64][65];
    const int dt = blockIdx.x, ht = blockIdx.y, n = blockIdx.z;
    const int tid = threadIdx.x;
    {
        int r = tid >> 2, cg = (tid & 3) << 4;
        int h = ht * 64 + r;
        if (h < HDIM) {
            const float* src = W2 + (size_t)(n * HDIM + h) * 512 + dt * 64 + cg;
            float4 v0 = *(const float4*)&src[0];
            float4 v1 = *(const float4*)&src[4];
            float4 v2 = *(const float4*)&src[8];
            float4 v3 = *(const float4*)&src[12];
            *(float4*)&Ls[r][cg + 0]  = v0; *(float4*)&Ls[r][cg + 4]  = v1;
            *(float4*)&Ls[r][cg + 8]  = v2; *(float4*)&Ls[r][cg + 12] = v3;
        } else {
            #pragma unroll
            for (int i = 0; i < 16; ++i) Ls[r][cg + i] = 0.f;
        }
    }
    __syncthreads();
    {
        int cc = tid & 63, kq = tid >> 6;
        u16 tmp[16];
        #pragma unroll
        for (int i = 0; i < 16; ++i) tmp[i] = f2bf(Ls[kq * 16 + i][cc]);
        u16* dst = W2T + (size_t)(dt * 64 + cc) * NHPCOL + n * HPAD + ht * 64 + kq * 16;
        *(uint4*)dst = *(uint4*)&tmp[0];
        *(uint4*)(dst + 8) = *(uint4*)&tmp[8];
    }
}

// ---------------------------------------------------------------------------
// Wout[8192][512] -> WoutT[o][k] bf16.  grid (kt=128, ot=8)
// ---------------------------------------------------------------------------
__global__ __launch_bounds__(256) void k_t_wout(const float* __restrict__ W, u16* __restrict__ WT) {
    __shared__ float Ls[64][65];
    const int kt = blockIdx.x, ot = blockIdx.y;
    const int tid = threadIdx.x;
    {
        int r = tid >> 2, cg = (tid & 3) << 4;
        const float* src = W + (size_t)(kt * 64 + r) * 512 + ot * 64 + cg;
        float4 v0 = *(const float4*)&src[0];
        float4 v1 = *(const float4*)&src[4];
        float4 v2 = *(const float4*)&src[8];
        float4 v3 = *(const float4*)&src[12];
        *(float4*)&Ls[r][cg + 0]  = v0; *(float4*)&Ls[r][cg + 4]  = v1;
        *(float4*)&Ls[r][cg + 8]  = v2; *(float4*)&Ls[r][cg + 12] = v3;
    }
    __syncthreads();
    {
        int cc = tid & 63, kq = tid >> 6;
        u16 tmp[16];
        #pragma unroll
        for (int i = 0; i < 16; ++i) tmp[i] = f2bf(Ls[kq * 16 + i][cc]);
        u16* dst = WT + (size_t)(ot * 64 + cc) * 8192 + kt * 64 + kq * 16;
        *(uint4*)dst = *(uint4*)&tmp[0];
        *(uint4*)(dst + 8) = *(uint4*)&tmp[8];
    }
}

// ---------------------------------------------------------------------------
// Dw softmax over m  ->  DwT[b][n][p(704, zero-pad)][16 m] bf16
// grid (44, 16)
// ---------------------------------------------------------------------------
__global__ __launch_bounds__(256) void k_dw(const float* __restrict__ L, u16* __restrict__ DwT) {
    const int b = blockIdx.y;
    const int c = blockIdx.x * 256 + threadIdx.x;      // n*704+p
    const int n = c / HPAD, p = c - n * HPAD;
    u16 o[16];
    if (p < HDIM) {
        float v[16];
        float mx = -1e30f;
        #pragma unroll
        for (int m = 0; m < 16; ++m) {
            v[m] = L[(b * 16 + m) * NHCOL + n * HDIM + p];
            mx = fmaxf(mx, v[m]);
        }
        float s = 0.f;
        #pragma unroll
        for (int m = 0; m < 16; ++m) { v[m] = expf(v[m] - mx); s += v[m]; }
        float inv = 1.f / s;
        #pragma unroll
        for (int m = 0; m < 16; ++m) o[m] = f2bf(v[m] * inv);
    } else {
        #pragma unroll
        for (int m = 0; m < 16; ++m) o[m] = 0;
    }
    u16* dst = DwT + (size_t)((b * 16 + n) * HPAD + p) * 16;
    *(uint4*)dst = *(uint4*)&o[0];
    *(uint4*)(dst + 8) = *(uint4*)&o[8];
}

// ---------------------------------------------------------------------------
// Cw = softmax_p(softmax_n(logits)) -> CwB[b][n][m][704 p] bf16 (zero-pad p)
// block per (m=bx, b=by); phase A caches exp(s1) in LDS so phase B does no exp
// ---------------------------------------------------------------------------
__global__ __launch_bounds__(256) void k_cw(const float* __restrict__ L, u16* __restrict__ CwB) {
    const int m = blockIdx.x, b = blockIdx.y;
    __shared__ float row[NHCOL];
    const int tid = threadIdx.x;
    const float* Lrow = L + (size_t)(b * 16 + m) * NHCOL;
    for (int i = tid; i < NHCOL; i += 256) row[i] = Lrow[i];
    __syncthreads();
    for (int p = tid; p < HDIM; p += 256) {
        float v[16];
        float mx = -1e30f;
        #pragma unroll
        for (int n = 0; n < 16; ++n) { v[n] = row[n * HDIM + p]; mx = fmaxf(mx, v[n]); }
        float s = 0.f;
        #pragma unroll
        for (int n = 0; n < 16; ++n) { v[n] = expf(v[n] - mx); s += v[n]; }
        float inv = 1.f / s;
        #pragma unroll
        for (int n = 0; n < 16; ++n) row[n * HDIM + p] = expf(v[n] * inv);  // cache exp(s1)
    }
    __syncthreads();
    const int wv = tid >> 6, lane = tid & 63;
    for (int nn = 0; nn < 4; ++nn) {
        int n = wv * 4 + nn;
        float s = 0.f;
        for (int p = lane; p < HDIM; p += 64) s += row[n * HDIM + p];
        #pragma unroll
        for (int off = 32; off > 0; off >>= 1) s += __shfl_xor(s, off);
        float inv = 1.f / s;
        u16* dst = CwB + (size_t)(((b * 16 + n) * 16 + m)) * HPAD;
        for (int p = lane; p < HDIM; p += 64) dst[p] = f2bf(row[n * HDIM + p] * inv);
        if (lane < HPAD - HDIM) dst[HDIM + lane] = 0;
    }
}

// ---------------------------------------------------------------------------
// MFMA GEMM: T1b[256][11264] bf16 = xb_hi[256][512] * W1T^T
// grid (ct=88, rt=2); 128x128 tile, 4 waves of 64x64
// ---------------------------------------------------------------------------
__global__ __launch_bounds__(256) void k_t1gemm(
    const u16* __restrict__ A, const u16* __restrict__ BT, u16* __restrict__ C) {
    __shared__ u16 AsL[128 * 40];
    __shared__ u16 BsL[128 * 40];
    const int ct = blockIdx.x, rt = blockIdx.y;
    const int tid = threadIdx.x;
    const int wv = tid >> 6, lane = tid & 63, quad = lane >> 4, l15 = lane & 15;
    const int mb = (wv & 1) * 64, nb = (wv >> 1) * 64;
    f32x4 acc[4][4] = {};
    for (int kb = 0; kb < 512; kb += 32) {
        {
            int r = tid >> 1, kg = (tid & 1) * 16;
            const u16* s = A + (size_t)(rt * 128 + r) * 512 + kb + kg;
            *(uint4*)&AsL[r * 40 + kg]     = *(const uint4*)s;
            *(uint4*)&AsL[r * 40 + kg + 8] = *(const uint4*)(s + 8);
            const u16* t = BT + (size_t)(ct * 128 + r) * 512 + kb + kg;
            *(uint4*)&BsL[r * 40 + kg]     = *(const uint4*)t;
            *(uint4*)&BsL[r * 40 + kg + 8] = *(const uint4*)(t + 8);
        }
        __syncthreads();
        bf16x8 af[4], bf[4];
        #pragma unroll
        for (int i = 0; i < 4; ++i) {
            af[i] = *(const bf16x8*)&AsL[(mb + i * 16 + l15) * 40 + quad * 8];
            bf[i] = *(const bf16x8*)&BsL[(nb + i * 16 + l15) * 40 + quad * 8];
        }
        #pragma unroll
        for (int i = 0; i < 4; ++i)
            #pragma unroll
            for (int j = 0; j < 4; ++j)
                acc[i][j] = __builtin_amdgcn_mfma_f32_16x16x32_bf16(af[i], bf[j], acc[i][j], 0, 0, 0);
        __syncthreads();
    }
    #pragma unroll
    for (int i = 0; i < 4; ++i)
        #pragma unroll
        for (int j = 0; j < 4; ++j) {
            int col = ct * 128 + nb + j * 16 + l15;
            int r0  = rt * 128 + mb + i * 16 + quad * 4;
            #pragma unroll
            for (int r = 0; r < 4; ++r)
                C[(size_t)(r0 + r) * NHPCOL + col] = f2bf(acc[i][j][r]);
        }
}

// ---------------------------------------------------------------------------
// Fused middle (MFMA): per (htile, n, b):
//   hmid[p][h] = relu(b1[h] + sum_m Dw[m][p]*T1[m][h])   (K=16, zero-padded)
//   G[m][h]   += sum_p Cw[m][p]*hmid[p][h]
// grid (6, 16, 16)
// ---------------------------------------------------------------------------
__global__ __launch_bounds__(256) void k_mid(
    const u16* __restrict__ T1b, const u16* __restrict__ DwT,
    const u16* __restrict__ CwB, const float* __restrict__ b1,
    u16* __restrict__ Gb) {
    __shared__ u16 T1T[128 * 24];
    __shared__ u16 hmidT[128 * 72];
    const int ht = blockIdx.x, n = blockIdx.y, b = blockIdx.z;
    const int tid = threadIdx.x;
    const int wv = tid >> 6, lane = tid & 63, quad = lane >> 4, l15 = lane & 15;
    const int h0 = ht * 128;
    const int b16n = b * 16 + n;

    {
        int m = tid & 15, hh0 = (tid >> 4) * 8;
        u16 v[8];
        if (h0 + hh0 < HPAD) {
            *(uint4*)v = *(const uint4*)(T1b + (size_t)(b * 16 + m) * NHPCOL + n * HPAD + h0 + hh0);
        } else {
            #pragma unroll
            for (int i = 0; i < 8; ++i) v[i] = 0;
        }
        #pragma unroll
        for (int i = 0; i < 8; ++i) T1T[(hh0 + i) * 24 + m] = v[i];
    }
    __syncthreads();

    bf16x8 bt1[2];
    float biasv[2];
    #pragma unroll
    for (int hj = 0; hj < 2; ++hj) {
        bf16x8 z = {};
        bt1[hj] = z;
        if (lane < 32)
            bt1[hj] = *(const bf16x8*)&T1T[(wv * 32 + hj * 16 + l15) * 24 + quad * 8];
        int h = h0 + wv * 32 + hj * 16 + l15;
        biasv[hj] = (h < HDIM) ? b1[n * HDIM + h] : 0.f;
    }

    f32x4 acc[2] = {};
    for (int c = 0; c < 11; ++c) {
        const int p0 = c * 64;
        #pragma unroll
        for (int pi = 0; pi < 4; ++pi) {
            bf16x8 adw = {};
            if (lane < 32)
                adw = *(const bf16x8*)(DwT + (size_t)((b16n * HPAD) + p0 + pi * 16 + l15) * 16 + quad * 8);
            #pragma unroll
            for (int hj = 0; hj < 2; ++hj) {
                f32x4 z = {};
                f32x4 hm = __builtin_amdgcn_mfma_f32_16x16x32_bf16(adw, bt1[hj], z, 0, 0, 0);
                u16 pk[4];
                #pragma unroll
                for (int r = 0; r < 4; ++r) pk[r] = f2bf(fmaxf(hm[r] + biasv[hj], 0.f));
                int hrow = wv * 32 + hj * 16 + l15;
                *(uint2*)&hmidT[hrow * 72 + pi * 16 + quad * 4] =
                    make_uint2((u32)pk[0] | ((u32)pk[1] << 16), (u32)pk[2] | ((u32)pk[3] << 16));
            }
        }
        #pragma unroll
        for (int s = 0; s < 2; ++s) {
            bf16x8 acw = *(const bf16x8*)(CwB + (size_t)(b16n * 16 + l15) * HPAD + p0 + s * 32 + quad * 8);
            #pragma unroll
            for (int hj = 0; hj < 2; ++hj) {
                bf16x8 bh = *(const bf16x8*)&hmidT[(wv * 32 + hj * 16 + l15) * 72 + s * 32 + quad * 8];
                acc[hj] = __builtin_amdgcn_mfma_f32_16x16x32_bf16(acw, bh, acc[hj], 0, 0, 0);
            }
        }
    }
    #pragma unroll
    for (int hj = 0; hj < 2; ++hj) {
        int h = h0 + wv * 32 + hj * 16 + l15;
        if (h < HPAD) {
            #pragma unroll
            for (int r = 0; r < 4; ++r) {
                int m = quad * 4 + r;
                Gb[(size_t)(b * 16 + m) * NHPCOL + n * HPAD + h] = f2bf(acc[hj][r]);
            }
        }
    }
}

// ---------------------------------------------------------------------------
// Init: Y[bm][d] = sum_n b2[n][d];  out[b][o] = bout[o]
// grid 544 (512 for Y, 32 for out)
// ---------------------------------------------------------------------------
__global__ __launch_bounds__(256) void k_init(
    const float* __restrict__ b2, const float* __restrict__ bout,
    float* __restrict__ Y, float* __restrict__ out) {
    const int bid = blockIdx.x, tid = threadIdx.x;
    if (bid < 512) {
        int idx = bid * 256 + tid;
        int d = idx & 511;
        float s = 0.f;
        #pragma unroll
        for (int nn = 0; nn < 16; ++nn) s += b2[nn * 512 + d];
        Y[idx] = s;
    } else {
        int idx = (bid - 512) * 256 + tid;
        out[idx] = bout[idx & 511];
    }
}

// ---------------------------------------------------------------------------
// MFMA split-K GEMM: Y[256][512] += Gb[.., n-slice] * W2T[d][n-slice]^T
// grid (ct=4, rt=4, n=16); 64x128 tile, 4 waves of 64x32
// ---------------------------------------------------------------------------
__global__ __launch_bounds__(256) void k_ygemm(
    const u16* __restrict__ G, const u16* __restrict__ W2T, float* __restrict__ Y) {
    __shared__ u16 AsL[64 * 40];
    __shared__ u16 BsL[128 * 40];
    const int ct = blockIdx.x, rt = blockIdx.y, n = blockIdx.z;
    const int tid = threadIdx.x;
    const int wv = tid >> 6, lane = tid & 63, quad = lane >> 4, l15 = lane & 15;
    const int m0 = rt * 64, d0 = ct * 128;
    f32x4 acc[4][2] = {};
    for (int kb = 0; kb < HPAD; kb += 32) {
        {
            int am = tid >> 2, akg = (tid & 3) * 8;
            *(uint4*)&AsL[am * 40 + akg] =
                *(const uint4*)(G + (size_t)(m0 + am) * NHPCOL + n * HPAD + kb + akg);
            int bc = tid >> 1, bkg = (tid & 1) * 16;
            const u16* t = W2T + (size_t)(d0 + bc) * NHPCOL + n * HPAD + kb + bkg;
            *(uint4*)&BsL[bc * 40 + bkg]     = *(const uint4*)t;
            *(uint4*)&BsL[bc * 40 + bkg + 8] = *(const uint4*)(t + 8);
        }
        __syncthreads();
        bf16x8 af[4], bf[2];
        #pragma unroll
        for (int i = 0; i < 4; ++i) af[i] = *(const bf16x8*)&AsL[(i * 16 + l15) * 40 + quad * 8];
        #pragma unroll
        for (int j = 0; j < 2; ++j) bf[j] = *(const bf16x8*)&BsL[(wv * 32 + j * 16 + l15) * 40 + quad * 8];
        #pragma unroll
        for (int i = 0; i < 4; ++i)
            #pragma unroll
            for (int j = 0; j < 2; ++j)
                acc[i][j] = __builtin_amdgcn_mfma_f32_16x16x32_bf16(af[i], bf[j], acc[i][j], 0, 0, 0);
        __syncthreads();
    }
    #pragma unroll
    for (int i = 0; i < 4; ++i)
        #pragma unroll
        for (int j = 0; j < 2; ++j) {
            int d = d0 + wv * 32 + j * 16 + l15;
            int r0 = m0 + i * 16 + quad * 4;
            #pragma unroll
            for (int r = 0; r < 4; ++r)
                atomicAdd(&Y[(size_t)(r0 + r) * 512 + d], acc[i][j][r]);
        }
}

// ---------------------------------------------------------------------------
// MFMA split-K GEMM: out[16][512] += Yflat[16][k-slice] * WoutT[o][k-slice]^T
// grid (ct=4, ks=16)
// ---------------------------------------------------------------------------
__global__ __launch_bounds__(256) void k_outgemm(
    const float* __restrict__ Y, const u16* __restrict__ WoutT, float* __restrict__ out) {
    __shared__ u16 AsL[16 * 40];
    __shared__ u16 BsL[128 * 40];
    const int ct = blockIdx.x, ks = blockIdx.y;
    const int tid = threadIdx.x;
    const int wv = tid >> 6, lane = tid & 63, quad = lane >> 4, l15 = lane & 15;
    const int o0 = ct * 128, kbase = ks * 512;
    f32x4 acc[2] = {};
    for (int kb = 0; kb < 512; kb += 32) {
        {
            int r = tid >> 4, k2 = (tid & 15) * 2;
            float2 v = *(const float2*)&Y[(size_t)r * 8192 + kbase + kb + k2];
            AsL[r * 40 + k2]     = f2bf(v.x);
            AsL[r * 40 + k2 + 1] = f2bf(v.y);
            int bc = tid >> 1, bkg = (tid & 1) * 16;
            const u16* t = WoutT + (size_t)(o0 + bc) * 8192 + kbase + kb + bkg;
            *(uint4*)&BsL[bc * 40 + bkg]     = *(const uint4*)t;
            *(uint4*)&BsL[bc * 40 + bkg + 8] = *(const uint4*)(t + 8);
        }
        __syncthreads();
        bf16x8 af = *(const bf16x8*)&AsL[l15 * 40 + quad * 8];
        #pragma unroll
        for (int j = 0; j < 2; ++j) {
            bf16x8 bf = *(const bf16x8*)&BsL[(wv * 32 + j * 16 + l15) * 40 + quad * 8];
            acc[j] = __builtin_amdgcn_mfma_f32_16x16x32_bf16(af, bf, acc[j], 0, 0, 0);
        }
        __syncthreads();
    }
    #pragma unroll
    for (int j = 0; j < 2; ++j) {
        int o = o0 + wv * 32 + j * 16 + l15;
        #pragma unroll
        for (int r = 0; r < 4; ++r)
            atomicAdd(&out[(size_t)(quad * 4 + r) * 512 + o], acc[j][r]);
    }
}

// ---------------------------------------------------------------------------
extern "C" void kernel_launch(void* const* d_in, const int* in_sizes, int n_in,
                              void* d_out, int out_size, void* d_ws, size_t ws_size,
                              hipStream_t stream) {
    const float* x    = (const float*)d_in[0];
    const float* phi  = (const float*)d_in[1];
    const float* W1   = (const float*)d_in[2];
    const float* b1   = (const float*)d_in[3];
    const float* W2   = (const float*)d_in[4];
    const float* b2   = (const float*)d_in[5];
    const float* Wout = (const float*)d_in[6];
    const float* bout = (const float*)d_in[7];
    float* out = (float*)d_out;

    char* base = (char*)d_ws;
    float* logits = (float*)(base + 0);            // 11,173,888 B
    u16*   DwT    = (u16*)(base + 11173888);       //  5,767,168
    u16*   CwB    = (u16*)(base + 16941056);       //  5,767,168
    u16*   T1b    = (u16*)(base + 22708224);       //  5,767,168
    u16*   Gb     = (u16*)(base + 28475392);       //  5,767,168
    u16*   xb     = (u16*)(base + 34242560);       //    262,144
    u16*   W1T    = (u16*)(base + 34504704);       // 11,534,336
    u16*   W2T    = (u16*)(base + 46039040);       // 11,534,336
    u16*   WoutT  = (u16*)(base + 57573376);       //  8,388,608
    float* Y      = (float*)(base + 65961984);     //    524,288
    u16*   xlo    = (u16*)(base + 66486272);       //    262,144 (end 66,748,416)
    // phiT hi/lo alias the DwT..Gb region (dead until after k_lgemm; stream serial)
    u16*   phiTh  = (u16*)(base + 11173888);       // 11,206,656 (CPAD*512*2)
    u16*   phiTl  = (u16*)(base + 22380544);       // 11,206,656 (ends 33,587,200 < Gb end)

    k_split_x <<<dim3(128), 256, 0, stream>>>(x, xb, xlo);
    k_t_phi   <<<dim3(8, 171), 256, 0, stream>>>(phi, phiTh, phiTl);
    k_lgemm   <<<dim3(171, 4), 256, 0, stream>>>(xb, xlo, phiTh, phiTl, logits);
    k_dw      <<<dim3(44, 16), 256, 0, stream>>>(logits, DwT);
    k_cw      <<<dim3(16, 16), 256, 0, stream>>>(logits, CwB);
    k_t_w1    <<<dim3(8, 11, 16), 256, 0, stream>>>(W1, W1T);
    k_t1gemm  <<<dim3(88, 2), 256, 0, stream>>>(xb, W1T, T1b);
    k_mid     <<<dim3(6, 16, 16), 256, 0, stream>>>(T1b, DwT, CwB, b1, Gb);
    k_t_w2    <<<dim3(8, 11, 16), 256, 0, stream>>>(W2, W2T);
    k_t_wout  <<<dim3(128, 8), 256, 0, stream>>>(Wout, WoutT);
    k_init    <<<dim3(544), 256, 0, stream>>>(b2, bout, Y, out);
    k_ygemm   <<<dim3(4, 4, 16), 256, 0, stream>>>(Gb, W2T, Y);
    k_outgemm <<<dim3(4, 16), 256, 0, stream>>>(Y, WoutT, out);
}